// Round 1
// baseline (95840.741 us; speedup 1.0000x reference)
//
#include <hip/hip_runtime.h>
#include <math.h>

#define NN 1024
#define PP 20

// ---------- cost: replicate reference fp32 op order exactly ----------
// diff fp32, square+add (no FMA contraction), sqrtf (HIP default: correctly
// rounded), sequential sum over P, divide by 20.
__device__ __forceinline__ float cost_ij(const float* __restrict__ a,
                                         const float* __restrict__ b) {
#pragma clang fp contract(off)
  float s = 0.0f;
#pragma unroll
  for (int p = 0; p < PP; ++p) {
    float dx = a[2 * p]     - b[2 * p];
    float dy = a[2 * p + 1] - b[2 * p + 1];
    s += sqrtf(dx * dx + dy * dy);
  }
  return s / 20.0f;
}

__device__ __forceinline__ float cost_fly(const float* __restrict__ a,
                                          const float* gx, const float* gy) {
#pragma clang fp contract(off)
  float s = 0.0f;
#pragma unroll
  for (int p = 0; p < PP; ++p) {
    float dx = a[2 * p]     - gx[p];
    float dy = a[2 * p + 1] - gy[p];
    s += sqrtf(dx * dx + dy * dy);
  }
  return s / 20.0f;
}

__global__ void cost_kernel(const float* __restrict__ pred,
                            const float* __restrict__ gt,
                            float* __restrict__ cost) {
  int id = blockIdx.x * blockDim.x + threadIdx.x;  // 0 .. NN*NN-1
  int i = id >> 10;
  int j = id & (NN - 1);
  cost[id] = cost_ij(pred + i * 40, gt + j * 40);
}

// ---------- LAP: Jonker-Volgenant shortest augmenting path ----------
// One persistent block, 1024 threads (one per column). All algorithm state in
// LDS. Replicates the reference numpy fp64 arithmetic bit-exactly, including
// argmin first-index tie-break.
template <bool USE_COST>
__global__ __launch_bounds__(1024) void lap_kernel(
    const float* __restrict__ pred, const float* __restrict__ gt,
    const float* __restrict__ cost, float* __restrict__ out) {
  const int t = threadIdx.x;

  __shared__ double u_s[NN];
  __shared__ double v_s[NN];
  __shared__ double shortest[NN];
  __shared__ int path[NN];
  __shared__ int col4row_s[NN];
  __shared__ int row4col_s[NN];
  __shared__ unsigned char SC[NN];
  __shared__ unsigned char SR[NN];
  __shared__ double rkey[16];
  __shared__ int ridx[16];
  __shared__ int cur_i_s;
  __shared__ int sink_s;
  __shared__ double minval_s;

  const double INF = __builtin_inf();

  // On-the-fly path: cache this thread's gt row (column t) in registers.
  float gx[PP], gy[PP];
  if (!USE_COST) {
#pragma unroll
    for (int p = 0; p < PP; ++p) {
      gx[p] = gt[t * 40 + 2 * p];
      gy[p] = gt[t * 40 + 2 * p + 1];
    }
  }

  u_s[t] = 0.0;
  v_s[t] = 0.0;
  col4row_s[t] = -1;
  row4col_s[t] = -1;
  __syncthreads();

  for (int r = 0; r < NN; ++r) {
    shortest[t] = INF;
    path[t] = -1;
    SC[t] = 0;
    SR[t] = 0;
    if (t == 0) {
      cur_i_s = r;
      minval_s = 0.0;
      sink_s = -1;
    }
    __syncthreads();

    while (true) {
      const int i = cur_i_s;
      const double mv = minval_s;

      double key = INF;
      if (!SC[t]) {
        float c;
        if (USE_COST) c = cost[i * NN + t];
        else          c = cost_fly(pred + i * 40, gx, gy);
        // exact numpy order: ((min_val + c) - u[i]) - v[j]
        double d = mv + (double)c;
        d -= u_s[i];
        d -= v_s[t];
        if (d < shortest[t]) {
          shortest[t] = d;
          path[t] = i;
        }
        key = shortest[t];
      }

      // lexicographic (key, idx) min over 64 lanes
      double k = key;
      int kidx = t;
#pragma unroll
      for (int m = 1; m < 64; m <<= 1) {
        double k2 = __shfl_xor(k, m);
        int i2 = __shfl_xor(kidx, m);
        if (k2 < k || (k2 == k && i2 < kidx)) { k = k2; kidx = i2; }
      }
      if ((t & 63) == 0) {
        rkey[t >> 6] = k;
        ridx[t >> 6] = kidx;
      }
      __syncthreads();

      if (t < 64) {
        double kk;
        int ii;
        if (t < 16) { kk = rkey[t]; ii = ridx[t]; }
        else        { kk = INF;     ii = 0x7fffffff; }
#pragma unroll
        for (int m = 1; m < 16; m <<= 1) {
          double k2 = __shfl_xor(kk, m);
          int i2 = __shfl_xor(ii, m);
          if (k2 < kk || (k2 == kk && i2 < ii)) { kk = k2; ii = i2; }
        }
        if (t == 0) {
          const int kcol = ii;
          minval_s = kk;       // == shortest[kcol], bit-identical
          SC[kcol] = 1;
          SR[i] = 1;           // reference sets SR[i]=True on loop entry
          const int rc = row4col_s[kcol];
          if (rc < 0) sink_s = kcol;
          else        cur_i_s = rc;
        }
      }
      __syncthreads();
      if (sink_s >= 0) break;
    }

    // dual update (pre-augmentation col4row, exact numpy op order)
    {
      const double mv = minval_s;
      if (t == r) {
        u_s[t] += mv;
      } else if (SR[t]) {
        u_s[t] += mv - shortest[col4row_s[t]];
      }
      if (SC[t]) {
        v_s[t] -= mv - shortest[t];
      }
      __syncthreads();
      if (t == 0) {
        int j = sink_s;
        while (true) {
          const int i2 = path[j];
          row4col_s[j] = i2;
          const int jn = col4row_s[i2];
          col4row_s[i2] = j;
          j = jn;
          if (i2 == r) break;
        }
      }
      __syncthreads();
    }
  }

  // ---------- outputs ----------
  // matched[t] = gt[col4row[t]] (N == M case: row_ind == arange(N))
  const int col = col4row_s[t];
  const float4* g4 = reinterpret_cast<const float4*>(gt + col * 40);
  float4* o4 = reinterpret_cast<float4*>(out + t * 40);
#pragma unroll
  for (int q = 0; q < 10; ++q) o4[q] = g4[q];

  float c;
  if (USE_COST) c = cost[t * NN + col];
  else          c = cost_ij(pred + t * 40, gt + col * 40);
  out[NN * 40 + t] = expf(-c);
}

extern "C" void kernel_launch(void* const* d_in, const int* in_sizes, int n_in,
                              void* d_out, int out_size, void* d_ws,
                              size_t ws_size, hipStream_t stream) {
  const float* pred = (const float*)d_in[0];
  const float* gt = (const float*)d_in[1];
  float* out = (float*)d_out;
  float* cost = (float*)d_ws;

  const size_t cost_bytes = (size_t)NN * NN * sizeof(float);
  if (ws_size >= cost_bytes) {
    cost_kernel<<<NN * NN / 256, 256, 0, stream>>>(pred, gt, cost);
    lap_kernel<true><<<1, NN, 0, stream>>>(pred, gt, cost, out);
  } else {
    lap_kernel<false><<<1, NN, 0, stream>>>(pred, gt, nullptr, out);
  }
}